// Round 4
// baseline (145.658 us; speedup 1.0000x reference)
//
#include <hip/hip_runtime.h>
#include <math.h>

#define N_TOTAL 8192
#define BHALF   4096
#define KDIM    128
#define NTILES  64                      // 8192 / 128
#define NBLK    (NTILES * (NTILES + 1) / 2)   // 2080 triangular tiles

typedef __bf16 bf16x8 __attribute__((ext_vector_type(8)));
typedef __bf16 bf16x2 __attribute__((ext_vector_type(2)));
typedef float  f32x4  __attribute__((ext_vector_type(4)));

// async global->LDS, 16B per lane; LDS dest must be lane-contiguous.
#define GLOAD_LDS16(GSRC, LDST)                                                \
    __builtin_amdgcn_global_load_lds(                                          \
        (const __attribute__((address_space(1))) void*)(GSRC),                 \
        (__attribute__((address_space(3))) void*)(LDST), 16, 0, 0)

// ---------------------------------------------------------------------------
// Kernel A (fused prep+pos): one wave per pair (i, i+BHALF).
//  - fp32 sq-norms (exact), bf16 copy of both rows, zero T,
//  - per-block positive-pair partial -> posPart[block]  (plain store, no
//    atomics, no memset needed),
//  - block 0 zeroes the ticket counter for kernel B.
// ---------------------------------------------------------------------------
__global__ __launch_bounds__(256) void k_prep_pos(const float* __restrict__ F,
                                                  __bf16* __restrict__ Fbf,
                                                  float* __restrict__ sq,
                                                  float* __restrict__ T,
                                                  float* __restrict__ posPart,
                                                  unsigned int* __restrict__ cnt) {
    int t = threadIdx.x;
    int w = t >> 6, l = t & 63;
    int p = blockIdx.x * 4 + w;          // pair index 0..4095
    const float2* r1 = (const float2*)(F + (size_t)p * KDIM);
    const float2* r2 = (const float2*)(F + (size_t)(p + BHALF) * KDIM);
    float2 a = r1[l];
    float2 c = r2[l];

    float s1 = fmaf(a.x, a.x, a.y * a.y);
    float s2 = fmaf(c.x, c.x, c.y * c.y);
    float dp = fmaf(a.x, c.x, a.y * c.y);
#pragma unroll
    for (int off = 32; off > 0; off >>= 1) {
        s1 += __shfl_down(s1, off);
        s2 += __shfl_down(s2, off);
        dp += __shfl_down(dp, off);
    }

    bf16x2 pa, pc;
    pa[0] = (__bf16)a.x; pa[1] = (__bf16)a.y;
    pc[0] = (__bf16)c.x; pc[1] = (__bf16)c.y;
    ((bf16x2*)(Fbf + (size_t)p * KDIM))[l] = pa;
    ((bf16x2*)(Fbf + (size_t)(p + BHALF) * KDIM))[l] = pc;

    __shared__ float posRed[4];
    if (l == 0) {
        sq[p] = s1;
        sq[p + BHALF] = s2;
        T[p] = 0.0f;
        T[p + BHALF] = 0.0f;
        float d2 = fmaxf(s1 + s2 - 2.0f * dp, 0.0f);
        posRed[w] = logf(1.0f + d2);
    }
    __syncthreads();
    if (t == 0) {
        posPart[blockIdx.x] = posRed[0] + posRed[1] + posRed[2] + posRed[3];
        if (blockIdx.x == 0) *cnt = 0u;
    }
}

// ---------------------------------------------------------------------------
// Kernel B: MFMA pairwise Cauchy row/col sums, 128x128 tiles, triangular grid,
// with fused final reduction via completion ticket (last block computes the
// scalar loss). 512 threads = 8 waves (4x2); each wave 32x64 as 2x4 frags of
// mfma_f32_16x16x32_bf16. 16B-granule XOR swizzle on the GLOBAL side of
// global_load_lds keeps the LDS dest lane-contiguous while spreading the
// fragment ds_read_b128s across all macro-banks.
// ---------------------------------------------------------------------------
__global__ __launch_bounds__(512, 4) void k_pairwise(
        const __bf16* __restrict__ Fbf,
        const float* __restrict__ sq,
        float* __restrict__ T,
        const float* __restrict__ posPart,
        unsigned int* __restrict__ cnt,
        float* __restrict__ out) {
    // triangular decode: block b -> (ti, tj), tj >= ti, 64x64 tile grid
    int b = blockIdx.x;
    int ti = (int)floorf((129.0f - sqrtf(16641.0f - 8.0f * (float)b)) * 0.5f);
    while (ti * (129 - ti) / 2 > b) --ti;
    while ((ti + 1) * (128 - ti) / 2 <= b) ++ti;
    int tj = ti + (b - ti * (129 - ti) / 2);
    int I = ti * 128, J = tj * 128;
    bool diag = (ti == tj);

    __shared__ __align__(16) __bf16 As[128 * 128];
    __shared__ __align__(16) __bf16 Bs[128 * 128];
    __shared__ float rowAcc[128][2];
    __shared__ float colAcc[128][4];
    __shared__ float finRed[8];
    __shared__ unsigned int ticket;

    int t = threadIdx.x;
    int w = t >> 6;              // wave 0..7
    int l = t & 63;
    int wr = w >> 1, wc = w & 1; // 4x2 wave grid
    int low = l & 15, kb = l >> 4;

    // ---- stage both 128x128 bf16 tiles (2048 granules each) ----
    const __bf16* FA = Fbf + (size_t)I * KDIM;
    const __bf16* FB = Fbf + (size_t)J * KDIM;
#pragma unroll
    for (int it = 0; it < 4; ++it) {
        int f = it * 512 + t;            // granule slot 0..2047
        int row = f >> 4;
        int sg = f & 15;
        int g = sg ^ (row & 15);         // global granule that lands here
        GLOAD_LDS16(FA + row * KDIM + g * 8, As + (size_t)f * 8);
        GLOAD_LDS16(FB + row * KDIM + g * 8, Bs + (size_t)f * 8);
    }
    __syncthreads();

    // ---- MFMA K-loop: 4 steps of K=32, 2x4 fragments per wave ----
    const bf16x8* Asg = (const bf16x8*)As;
    const bf16x8* Bsg = (const bf16x8*)Bs;
    f32x4 acc[2][4] = {};
#pragma unroll
    for (int s = 0; s < 4; ++s) {
        int g = s * 4 + kb;
        bf16x8 aF[2], bF[4];
#pragma unroll
        for (int fr = 0; fr < 2; ++fr) {
            int R = wr * 32 + fr * 16 + low;
            aF[fr] = Asg[R * 16 + (g ^ low)];
        }
#pragma unroll
        for (int fc = 0; fc < 4; ++fc) {
            int C = wc * 64 + fc * 16 + low;
            bF[fc] = Bsg[C * 16 + (g ^ low)];
        }
#pragma unroll
        for (int fr = 0; fr < 2; ++fr)
#pragma unroll
            for (int fc = 0; fc < 4; ++fc)
                acc[fr][fc] = __builtin_amdgcn_mfma_f32_16x16x32_bf16(
                    aF[fr], bF[fc], acc[fr][fc], 0, 0, 0);
    }

    // ---- epilogue: Cauchy + row/col partial sums ----
    // C/D layout: col = low, row = kb*4 + reg (within each 16x16 fragment)
    float sqi[2][4], sqj[4];
#pragma unroll
    for (int fr = 0; fr < 2; ++fr)
#pragma unroll
        for (int r = 0; r < 4; ++r)
            sqi[fr][r] = sq[I + wr * 32 + fr * 16 + kb * 4 + r];
#pragma unroll
    for (int fc = 0; fc < 4; ++fc)
        sqj[fc] = sq[J + wc * 64 + fc * 16 + low];

    float rowPart[2][4] = {};
    float colPart[4] = {0.f, 0.f, 0.f, 0.f};
#pragma unroll
    for (int fr = 0; fr < 2; ++fr) {
#pragma unroll
        for (int fc = 0; fc < 4; ++fc) {
#pragma unroll
            for (int r = 0; r < 4; ++r) {
                float d2 = sqi[fr][r] + sqj[fc] - 2.0f * acc[fr][fc][r];
                d2 = fmaxf(d2, 0.0f);
                float v = __builtin_amdgcn_rcpf(1.0f + d2);
                rowPart[fr][r] += v;
                colPart[fc] += v;
            }
        }
    }

    // row partials: reduce across the 16 lanes sharing a row (low)
#pragma unroll
    for (int fr = 0; fr < 2; ++fr)
#pragma unroll
        for (int r = 0; r < 4; ++r) {
            float x = rowPart[fr][r];
            x += __shfl_xor(x, 1);
            x += __shfl_xor(x, 2);
            x += __shfl_xor(x, 4);
            x += __shfl_xor(x, 8);
            if (low == 0)
                rowAcc[wr * 32 + fr * 16 + kb * 4 + r][wc] = x;
        }

    // col partials: reduce across the 4 lane-quads (kb)
#pragma unroll
    for (int fc = 0; fc < 4; ++fc) {
        float x = colPart[fc];
        x += __shfl_xor(x, 16);
        x += __shfl_xor(x, 32);
        if (kb == 0)
            colAcc[wc * 64 + fc * 16 + low][wr] = x;
    }
    __syncthreads();

    if (t < 128) {
        atomicAdd(&T[I + t], rowAcc[t][0] + rowAcc[t][1]);
    } else if (t < 256 && !diag) {
        int c = t - 128;
        atomicAdd(&T[J + c],
                  colAcc[c][0] + colAcc[c][1] + colAcc[c][2] + colAcc[c][3]);
    }
    __syncthreads();   // block's T atomics complete (vmcnt(0) before barrier)

    // ---- completion ticket: last block computes the scalar loss ----
    if (t == 0) {
        __threadfence();
        ticket = __hip_atomic_fetch_add(cnt, 1u, __ATOMIC_ACQ_REL,
                                        __HIP_MEMORY_SCOPE_AGENT);
    }
    __syncthreads();
    if (ticket != (unsigned int)(NBLK - 1)) return;

    // winner: all other blocks' T-adds are visible (agent-scope loads).
    float s = 0.0f;
    for (int i = t; i < N_TOTAL; i += 512) {
        float Ti = __hip_atomic_load(&T[i], __ATOMIC_RELAXED,
                                     __HIP_MEMORY_SCOPE_AGENT);
        s += logf(Ti - 1.0f);
    }
    s *= 0.5f;                           // -> /(2b) after /b below
    for (int i = t; i < 1024; i += 512) s += posPart[i];
#pragma unroll
    for (int off = 32; off > 0; off >>= 1) s += __shfl_down(s, off);
    if (l == 0) finRed[w] = s;
    __syncthreads();
    if (t == 0) {
        float S = 0.0f;
#pragma unroll
        for (int i = 0; i < 8; ++i) S += finRed[i];
        out[0] = S / (float)BHALF;
    }
}

// ---------------------------------------------------------------------------
extern "C" void kernel_launch(void* const* d_in, const int* in_sizes, int n_in,
                              void* d_out, int out_size, void* d_ws, size_t ws_size,
                              hipStream_t stream) {
    const float* F = (const float*)d_in[0];
    float* out = (float*)d_out;

    char* ws = (char*)d_ws;
    __bf16* Fbf     = (__bf16*)ws;                               // 2 MB
    float*  sq      = (float*)(ws + (size_t)N_TOTAL * KDIM * 2); // 8192 f
    float*  T       = sq + N_TOTAL;                              // 8192 f
    float*  posPart = T + N_TOTAL;                               // 1024 f
    unsigned int* cnt = (unsigned int*)(posPart + 1024);

    k_prep_pos<<<BHALF / 4, 256, 0, stream>>>(F, Fbf, sq, T, posPart, cnt);
    k_pairwise<<<NBLK, 512, 0, stream>>>(Fbf, sq, T, posPart, cnt, out);
}

// Round 5
// 98.606 us; speedup vs baseline: 1.4772x; 1.4772x over previous
//
#include <hip/hip_runtime.h>
#include <math.h>

#define N_TOTAL 8192
#define BHALF   4096
#define KDIM    128
#define NBLK    528     // sum_{si=0..31} (32 - si): 256-row strips, chunks of 2 col-tiles

typedef __bf16 bf16x8 __attribute__((ext_vector_type(8)));
typedef __bf16 bf16x2 __attribute__((ext_vector_type(2)));
typedef float  f32x4  __attribute__((ext_vector_type(4)));

// async global->LDS, 16B per lane; LDS dest must be lane-contiguous per wave.
#define GLOAD_LDS16(GSRC, LDST)                                                \
    __builtin_amdgcn_global_load_lds(                                          \
        (const __attribute__((address_space(1))) void*)(GSRC),                 \
        (__attribute__((address_space(3))) void*)(LDST), 16, 0, 0)

// ---------------------------------------------------------------------------
// Kernel A (fused prep+pos): one wave per pair (i, i+BHALF).
//  fp32 sq-norms (exact), bf16 copy of both rows, zero T,
//  per-block positive-pair partial -> posPart[block] (plain store).
// ---------------------------------------------------------------------------
__global__ __launch_bounds__(256) void k_prep_pos(const float* __restrict__ F,
                                                  __bf16* __restrict__ Fbf,
                                                  float* __restrict__ sq,
                                                  float* __restrict__ T,
                                                  float* __restrict__ posPart) {
    int t = threadIdx.x;
    int w = t >> 6, l = t & 63;
    int p = blockIdx.x * 4 + w;          // pair index 0..4095
    const float2* r1 = (const float2*)(F + (size_t)p * KDIM);
    const float2* r2 = (const float2*)(F + (size_t)(p + BHALF) * KDIM);
    float2 a = r1[l];
    float2 c = r2[l];

    float s1 = fmaf(a.x, a.x, a.y * a.y);
    float s2 = fmaf(c.x, c.x, c.y * c.y);
    float dp = fmaf(a.x, c.x, a.y * c.y);
#pragma unroll
    for (int off = 32; off > 0; off >>= 1) {
        s1 += __shfl_down(s1, off);
        s2 += __shfl_down(s2, off);
        dp += __shfl_down(dp, off);
    }

    bf16x2 pa, pc;
    pa[0] = (__bf16)a.x; pa[1] = (__bf16)a.y;
    pc[0] = (__bf16)c.x; pc[1] = (__bf16)c.y;
    ((bf16x2*)(Fbf + (size_t)p * KDIM))[l] = pa;
    ((bf16x2*)(Fbf + (size_t)(p + BHALF) * KDIM))[l] = pc;

    __shared__ float posRed[4];
    if (l == 0) {
        sq[p] = s1;
        sq[p + BHALF] = s2;
        T[p] = 0.0f;
        T[p + BHALF] = 0.0f;
        float d2 = fmaxf(s1 + s2 - 2.0f * dp, 0.0f);
        posRed[w] = logf(1.0f + d2);
    }
    __syncthreads();
    if (t == 0)
        posPart[blockIdx.x] = posRed[0] + posRed[1] + posRed[2] + posRed[3];
}

// ---------------------------------------------------------------------------
// Kernel B: strip-mined MFMA pairwise Cauchy row/col sums.
// Block = (strip si of 256 rows, chunk of exactly 2 col-tiles of 128 cols).
// A strip (256x128 bf16, 64 KB) staged once; B tiles double-buffered (2x32KB):
// B1 prefetched via global_load_lds during tile-0 compute; the tile-0 epilogue
// barrier's vmcnt(0) drain covers it (no explicit wait).
// 8 waves (4x2 grid); each wave owns 64x64 as 4x4 frags of 16x16x32 bf16
// -> 8 B/entry LDS-read traffic. Strictly-upper-triangle mask (C > R) on the
// 2 leading tiles of each strip; diagonal excluded (final uses log(T)).
// 16B-granule XOR swizzle applied on the GLOBAL side of global_load_lds.
// ---------------------------------------------------------------------------
__global__ __launch_bounds__(512, 2) void k_pairwise(
        const __bf16* __restrict__ Fbf,
        const float* __restrict__ sq,
        float* __restrict__ T) {
    // decode block -> (si, bl): strip si has 32-si chunks
    int b = blockIdx.x;
    int si = 0, cum = 0;
    while (cum + (32 - si) <= b) { cum += 32 - si; ++si; }
    int bl = b - cum;                 // chunk index within strip
    int cj0 = 2 * si + 2 * bl;        // first col-tile (always 2 tiles)
    int I0 = si * 256;
    bool masked = (bl == 0);          // leading 2 tiles straddle the diagonal

    __shared__ __align__(16) __bf16 As[256 * 128];      // 64 KB
    __shared__ __align__(16) __bf16 Bs[2][128 * 128];   // 2 x 32 KB
    __shared__ float rowAcc[256][2];
    __shared__ float colAcc[128][4];

    int t = threadIdx.x;
    int w = t >> 6;               // wave 0..7
    int l = t & 63;
    int wr = w >> 1, wc = w & 1;  // 4x2 wave grid (64x64 quadrants of 256x128)
    int low = l & 15, kb = l >> 4;

    // ---- prologue: stage A strip (4096 granules) + B0 (2048 granules) ----
    const __bf16* FA = Fbf + (size_t)I0 * KDIM;
    const __bf16* FB0 = Fbf + (size_t)cj0 * 128 * KDIM;
#pragma unroll
    for (int it = 0; it < 8; ++it) {
        int f = it * 512 + t;
        int row = f >> 4;
        int sg = f & 15;
        int g = sg ^ (row & 15);
        GLOAD_LDS16(FA + row * KDIM + g * 8, As + (size_t)f * 8);
    }
#pragma unroll
    for (int it = 0; it < 4; ++it) {
        int f = it * 512 + t;
        int row = f >> 4;
        int sg = f & 15;
        int g = sg ^ (row & 15);
        GLOAD_LDS16(FB0 + row * KDIM + g * 8, Bs[0] + (size_t)f * 8);
    }
    __syncthreads();

    const bf16x8* Asg = (const bf16x8*)As;
    float rowPart[4][4] = {};     // accumulates across BOTH tiles (same rows)

    float sqi[4][4];
#pragma unroll
    for (int fr = 0; fr < 4; ++fr)
#pragma unroll
        for (int r = 0; r < 4; ++r)
            sqi[fr][r] = sq[I0 + wr * 64 + fr * 16 + kb * 4 + r];

    for (int kt = 0; kt < 2; ++kt) {
        int tj = cj0 + kt;
        int J0 = tj * 128;

        // prefetch next B tile into the other buffer (issued before compute;
        // completion guaranteed by this tile's epilogue __syncthreads drain)
        if (kt == 0) {
            const __bf16* FB1 = Fbf + (size_t)(cj0 + 1) * 128 * KDIM;
#pragma unroll
            for (int it = 0; it < 4; ++it) {
                int f = it * 512 + t;
                int row = f >> 4;
                int sg = f & 15;
                int g = sg ^ (row & 15);
                GLOAD_LDS16(FB1 + row * KDIM + g * 8, Bs[1] + (size_t)f * 8);
            }
        }

        // ---- MFMA K-loop: 4 steps of K=32, 4x4 fragments per wave ----
        const bf16x8* Bsg = (const bf16x8*)Bs[kt];
        f32x4 acc[4][4] = {};
#pragma unroll
        for (int s = 0; s < 4; ++s) {
            int g = s * 4 + kb;
            bf16x8 aF[4], bF[4];
#pragma unroll
            for (int fr = 0; fr < 4; ++fr) {
                int R = wr * 64 + fr * 16 + low;
                aF[fr] = Asg[R * 16 + (g ^ low)];
            }
#pragma unroll
            for (int fc = 0; fc < 4; ++fc) {
                int C = wc * 64 + fc * 16 + low;
                bF[fc] = Bsg[C * 16 + (g ^ low)];
            }
#pragma unroll
            for (int fr = 0; fr < 4; ++fr)
#pragma unroll
                for (int fc = 0; fc < 4; ++fc)
                    acc[fr][fc] = __builtin_amdgcn_mfma_f32_16x16x32_bf16(
                        aF[fr], bF[fc], acc[fr][fc], 0, 0, 0);
        }

        // ---- epilogue: Cauchy + row/col partial sums ----
        // C/D layout: col = low, row = kb*4 + reg (within 16x16 fragment)
        float sqj[4];
#pragma unroll
        for (int fc = 0; fc < 4; ++fc)
            sqj[fc] = sq[J0 + wc * 64 + fc * 16 + low];

        float colPart[4] = {0.f, 0.f, 0.f, 0.f};
#define EPI(MASK)                                                              \
        _Pragma("unroll")                                                      \
        for (int fr = 0; fr < 4; ++fr) {                                       \
            _Pragma("unroll")                                                  \
            for (int fc = 0; fc < 4; ++fc) {                                   \
                _Pragma("unroll")                                              \
                for (int r = 0; r < 4; ++r) {                                  \
                    float d2 = sqi[fr][r] + sqj[fc] - 2.0f * acc[fr][fc][r];   \
                    d2 = fmaxf(d2, 0.0f);                                      \
                    float v = __builtin_amdgcn_rcpf(1.0f + d2);                \
                    if (MASK) {                                                \
                        int R = I0 + wr * 64 + fr * 16 + kb * 4 + r;           \
                        int C = J0 + wc * 64 + fc * 16 + low;                  \
                        v = (C > R) ? v : 0.0f;                                \
                    }                                                          \
                    rowPart[fr][r] += v;                                       \
                    colPart[fc] += v;                                          \
                }                                                              \
            }                                                                  \
        }
        if (masked) { EPI(true) } else { EPI(false) }
#undef EPI

        // col partials: reduce across the 4 lane-quads (kb), then cross-wave
#pragma unroll
        for (int fc = 0; fc < 4; ++fc) {
            float x = colPart[fc];
            x += __shfl_xor(x, 16);
            x += __shfl_xor(x, 32);
            if (kb == 0)
                colAcc[wc * 64 + fc * 16 + low][wr] = x;
        }
        __syncthreads();   // colAcc ready; also drains B prefetch (vmcnt 0)
        if (t < 128)
            atomicAdd(&T[J0 + t],
                      colAcc[t][0] + colAcc[t][1] + colAcc[t][2] + colAcc[t][3]);
        __syncthreads();   // colAcc consumed before next tile overwrites
    }

    // row partials (accumulated over both tiles): reduce across 16 col-lanes
#pragma unroll
    for (int fr = 0; fr < 4; ++fr)
#pragma unroll
        for (int r = 0; r < 4; ++r) {
            float x = rowPart[fr][r];
            x += __shfl_xor(x, 1);
            x += __shfl_xor(x, 2);
            x += __shfl_xor(x, 4);
            x += __shfl_xor(x, 8);
            if (low == 0)
                rowAcc[wr * 64 + fr * 16 + kb * 4 + r][wc] = x;
        }
    __syncthreads();
    if (t < 256)
        atomicAdd(&T[I0 + t], rowAcc[t][0] + rowAcc[t][1]);
}

// ---------------------------------------------------------------------------
// Kernel C: final scalar, single block (no memset/atomics needed).
// T excludes the diagonal, so neg term = mean log(T); loss = S_T/(2b)+S_pos/b.
// ---------------------------------------------------------------------------
__global__ __launch_bounds__(512) void k_final(const float* __restrict__ T,
                                               const float* __restrict__ posPart,
                                               float* __restrict__ out) {
    int t = threadIdx.x;
    float s = 0.0f;
    for (int i = t; i < N_TOTAL; i += 512) s += logf(T[i]);
    s *= 0.5f;
    for (int i = t; i < 1024; i += 512) s += posPart[i];
#pragma unroll
    for (int off = 32; off > 0; off >>= 1) s += __shfl_down(s, off);
    __shared__ float red[8];
    int w = t >> 6, l = t & 63;
    if (l == 0) red[w] = s;
    __syncthreads();
    if (t == 0) {
        float S = 0.0f;
#pragma unroll
        for (int i = 0; i < 8; ++i) S += red[i];
        out[0] = S / (float)BHALF;
    }
}

// ---------------------------------------------------------------------------
extern "C" void kernel_launch(void* const* d_in, const int* in_sizes, int n_in,
                              void* d_out, int out_size, void* d_ws, size_t ws_size,
                              hipStream_t stream) {
    const float* F = (const float*)d_in[0];
    float* out = (float*)d_out;

    char* ws = (char*)d_ws;
    __bf16* Fbf     = (__bf16*)ws;                               // 2 MB
    float*  sq      = (float*)(ws + (size_t)N_TOTAL * KDIM * 2); // 8192 f
    float*  T       = sq + N_TOTAL;                              // 8192 f
    float*  posPart = T + N_TOTAL;                               // 1024 f

    k_prep_pos<<<BHALF / 4, 256, 0, stream>>>(F, Fbf, sq, T, posPart);
    k_pairwise<<<NBLK, 512, 0, stream>>>(Fbf, sq, T);
    k_final<<<1, 512, 0, stream>>>(T, posPart, out);
}